// Round 15
// baseline (160.970 us; speedup 1.0000x reference)
//
#include <hip/hip_runtime.h>

#define N_PTS 50000
#define M 32
#define KP 15
#define D 64
#define E1 45
#define P 16       // points per block (512 threads, 8 waves)
#define WFS 1032   // wfh plane stride (ushorts): 1024 slots + 8 pad
#define AWR 36     // aw row stride inside plane (18 dw: odd mult -> <=2-way, free)

typedef __attribute__((ext_vector_type(8))) _Float16 f16x8;
typedef __attribute__((ext_vector_type(4))) float    f32x4;
typedef __attribute__((ext_vector_type(2))) _Float16 f16x2;
typedef __attribute__((ext_vector_type(2))) __fp16   fp16v2;   // builtin return type

__device__ __forceinline__ unsigned pkrtz(float a, float b) {   // packed fp16 RTZ
    union { fp16v2 v; unsigned u; } x;
    x.v = __builtin_amdgcn_cvt_pkrtz(a, b);
    return x.u;
}
__device__ __forceinline__ unsigned pkrne(float a, float b) {   // packed fp16 RNE
    union { f16x2 v; unsigned u; } x;
    x.v[0] = (_Float16)a; x.v[1] = (_Float16)b; return x.u;
}
__device__ __forceinline__ float h2f(unsigned bits16) {
    union { unsigned short s; _Float16 h; } x; x.s = (unsigned short)bits16;
    return (float)x.h;
}
// raw v_sqrt_f32 (~1-2 ulp): avoids libm's IEEE fixup expansion (~8-10 VALU).
// R9-verified: VALUBusy 54->38%, -8us. tol absmax~0.29.
__device__ __forceinline__ float fsqrt_fast(float x) {
#if __has_builtin(__builtin_amdgcn_sqrtf)
    return __builtin_amdgcn_sqrtf(x);
#else
    return sqrtf(x);
#endif
}
// compensated fp16 split (ow weight planes only)
__device__ __forceinline__ void split2h(float a, float b, unsigned& hu, unsigned& lu) {
    hu = pkrtz(a, b);
    const float ra = a - h2f(hu & 0xffffu);
    const float rb = b - h2f(hu >> 16);
    lu = pkrtz(ra, rb);
}

#if defined(__HIP_DEVICE_COMPILE__) && __has_builtin(__builtin_amdgcn_perm)
__device__ __forceinline__ unsigned permb(unsigned a, unsigned b, unsigned sel) {
    return __builtin_amdgcn_perm(a, b, sel);
}
#else
__device__ __forceinline__ unsigned permb(unsigned a, unsigned b, unsigned sel) {
    if (sel == 0x05040100u) return (b & 0xffffu) | (a << 16);
    return (b >> 16) | (a & 0xffff0000u);
}
#endif

// ---------------- fused prep (one launch; writes d_ws) -----------------------
// blocks [0,3125): x -> fp16-only rows: 6.4MB table, 128B per row.
//     layout (uint2 view): xw2[n*16 + c] = { pkrne(x[n][c],    x[n][16+c]),
//                                            pkrne(x[n][32+c], x[n][48+c]) }
// blocks [3125,3317): ow -> owh/owl fp16 planes (compensated); pos swizzle:
//     orig = pos ^ (((pos>>6)&3)<<2); d = orig>>4, k = orig&15 (zero pad k==15/e>=45)
// blocks [3317,3557): w -> wh single fp16 plane; pos = k*64+dsw, d = dsw ^ ((k&7)<<3)
__global__ void prep_all(const float* __restrict__ x, const float* __restrict__ ow,
                         const float* __restrict__ w, unsigned* __restrict__ xw,
                         unsigned short* __restrict__ owh, unsigned short* __restrict__ owl,
                         unsigned short* __restrict__ wh)
{
    const int b = blockIdx.x, tid = threadIdx.x;
    if (b < 3125) {
        const int i = b * 256 + tid;                 // [0, 800000) = one (n,c)
        const int n = i >> 4, c = i & 15;
        const float* src = x + n * 64 + c;           // 4 stride-16 reads, coalesced
        uint2 u;
        u.x = pkrne(src[0],  src[16]);               // {t0, t1}
        u.y = pkrne(src[32], src[48]);               // {t2, t3}
        ((uint2*)xw)[i] = u;                         // i == n*16+c, contiguous 8B
    } else if (b < 3317) {
        const int t = (b - 3125) * 256 + tid;               // [0, 49152)
        const int j = t & 7, lane = (t >> 3) & 63, rest = t >> 9;
        const int nt = rest % 3, ks = rest / 3;
        const int q = lane >> 4, c = lane & 15;
        const int pos  = ks * 32 + q * 8 + j;
        const int orig = pos ^ (((pos >> 6) & 3) << 2);
        const int d = orig >> 4, k = orig & 15, e = nt * 16 + c;
        const float v = (k < KP && e < E1) ? ow[k * (D * E1) + d * E1 + e] : 0.f;
        unsigned hu, lu; split2h(v, 0.f, hu, lu);
        owh[t] = (unsigned short)hu;
        owl[t] = (unsigned short)lu;
    } else {
        const int t = (b - 3317) * 256 + tid;               // [0, 61440)
        const int j = t & 7, lane = (t >> 3) & 63, rest = t >> 9;
        const int nt = rest & 3, ks = rest >> 2;            // ks in [0,30)
        const int q = lane >> 4, c = lane & 15;
        const int pos = ks * 32 + q * 8 + j;                // [0,960)
        const int k = pos >> 6, dsw = pos & 63;
        const int d = dsw ^ ((k & 7) << 3);
        const int e = nt * 16 + c;
        union { _Float16 h; unsigned short s; } cv;
        cv.h = (_Float16)w[k * (D * D) + d * D + e];        // RNE single fp16
        wh[t] = cv.s;
    }
}

// 512 threads (8 waves), 16 points/block, LDS 37,120 B -> 4 blocks/CU (32 waves).
__global__ __launch_bounds__(512, 8) void kpconv_deform(
    const float* __restrict__ qpts, const float* __restrict__ spts,
    const int*   __restrict__ nbrs, const float* __restrict__ kpts,
    const float* __restrict__ obias,
    const unsigned* __restrict__ xw,
    const unsigned short* __restrict__ owh, const unsigned short* __restrict__ owl,
    const unsigned short* __restrict__ wh,
    float* __restrict__ out)
{
    // wfh planes (16 x 1032 ushort = 33,024 B), now QUAD-duty:
    //   ph1->ph2: aw1 at plane slots [0,576), AWR=36 padded (R14's XOR layout was
    //             8-way conflicted: 16-dw row stride aliases rows 2 apart; 18-dw
    //             stride is the verified <=2-way layout). aw[p] is FULLY consumed
    //             by one b128 fragment read/wave at ph2 top, BEFORE enum writes
    //             to the same plane (same-wave LDS program order).
    //   ph2->ph3: wf1 fp16 enum (1024 slots/point)
    //   ph3->red: s_part3 [8][16][49] f32 = 25,088 B aliased (barrier-fenced)
    //   ph5->ph6: aw2 at plane slots [0,576) (same consume-then-overwrite idiom)
    //   ph6->ph7: wf2 single plane, k*64+dsw (writes cover [0,1024) fully)
    //   s_act:    pad hole at [w][1024] (ph5-write after part3 dead; read post-ph6)
    __shared__ __align__(16) unsigned short s_wfh[P][WFS];
    // misc block (4,096 B), dual-duty:
    //   s_nbr (1024 B, live ph1->ph2) + s_q (192 B, ph1) + s_off (2880 B, red->ph5)
    //   ph7: s_red [4][16][16] f32 = 4,096 B aliases ALL of it (all dead by ph7)
    __shared__ __align__(16) char s_misc[4096];
    unsigned short (*s_nbr)[M] = (unsigned short(*)[M])s_misc;         // 1024 B
    float (*s_q)[3]    = (float(*)[3])(s_misc + 1024);                 //  192 B
    float (*s_off)[E1] = (float(*)[E1])(s_misc + 1216);                // 2880 B
    float (*s_part3)[16][49] = (float(*)[16][49])s_wfh;
    float (*s_red)[16][16]   = (float(*)[16][16])s_misc;

    const int tid  = threadIdx.x;
    const int base = blockIdx.x * P;
    const int lane = tid & 63;
    const int wid  = tid >> 6;                  // 0..7
    const int q    = lane >> 4, c = lane & 15;
    const int pg   = tid >> 5, mg = tid & 31;   // (p,m) mapping for ph1/ph5
    // wave w's ph1/ph5 points {2w,2w+1} == its ph2/ph6 consumers -> no barrier needed

    float nbx, nby, nbz;   // centered neighbor coords, live ph1->ph5
    f16x8 fbh[2][4];       // cached x fp16 fragments (ph2 -> ph6)

    if (tid < P * 3)  ((float*)s_q)[tid]  = qpts[base * 3 + tid];
    __syncthreads();

    // ---- ph1: gather, centered nb, aw1 -> padded fp16 plane slots of wfh[pg] ----
    {
        const int ni = nbrs[(base + pg) * M + mg];
        s_nbr[pg][mg] = (unsigned short)ni;
        nbx = spts[ni * 3 + 0] - s_q[pg][0];
        nby = spts[ni * 3 + 1] - s_q[pg][1];
        nbz = spts[ni * 3 + 2] - s_q[pg][2];
        float av[16];
        av[15] = 0.f;                               // pad row -> exact zeros
#pragma unroll
        for (int k = 0; k < KP; k++) {              // kpts uniform -> scalar loads
            const float dx = nbx - kpts[k * 3 + 0];
            const float dy = nby - kpts[k * 3 + 1];
            const float dz = nbz - kpts[k * 3 + 2];
            av[k] = fmaxf(1.0f - fsqrt_fast(dx * dx + dy * dy + dz * dz), 0.f);
        }
        unsigned short* awp = &s_wfh[pg][0];
#pragma unroll
        for (int k2 = 0; k2 < 16; k2 += 2) {
            const unsigned hu = pkrne(av[k2], av[k2 + 1]);
            awp[k2 * AWR + mg]       = (unsigned short)hu;
            awp[(k2 + 1) * AWR + mg] = (unsigned short)(hu >> 16);
        }
    }
    // no barrier: ph2 wave reads only its own writes (lgkmcnt ordering)

    // ---- ph2: wf1 via single f16 MFMA (aw1 fp16, x fp16); cache x fragments ----
    {
        const int hc = c >> 2;
        const uint2* __restrict__ xwq = (const uint2*)xw;
#pragma unroll
        for (int pi = 0; pi < 2; pi++) {
            const int p = 2 * wid + pi;
            // consume aw1[p] fully (one b128/lane) BEFORE enum writes to plane p
            const f16x8 ah = *(const f16x8*)&s_wfh[p][(lane & 15) * AWR + q * 8];
            uint2 g2[8];                             // row-slices: {t01, t23} per (j,c)
#pragma unroll
            for (int j = 0; j < 8; j++)
                g2[j] = xwq[(int)s_nbr[p][q * 8 + j] * 16 + c];
#pragma unroll
            for (int t = 0; t < 4; t++) {
                union { f16x8 v; unsigned u[4]; } bh;
#pragma unroll
                for (int jj = 0; jj < 4; jj++) {    // pick t's half of each pair
                    const unsigned ga = (t < 2) ? g2[2 * jj + 1].x : g2[2 * jj + 1].y;
                    const unsigned gb = (t < 2) ? g2[2 * jj].x     : g2[2 * jj].y;
                    bh.u[jj] = permb(ga, gb, (t & 1) ? 0x07060302u : 0x05040100u);
                }
                fbh[pi][t] = bh.v;                   // cache for ph6
                f32x4 dacc = {0.f, 0.f, 0.f, 0.f};
                dacc = __builtin_amdgcn_mfma_f32_16x16x32_f16(ah, bh.v, dacc, 0, 0, 0);
                // wf1 -> single fp16 (RNE), swizzled enum:
                // pos = (t*16+c)*16 + 4*(q^hc) (+r)
                const unsigned u01 = pkrne(dacc[0], dacc[1]);
                const unsigned u23 = pkrne(dacc[2], dacc[3]);
                const int eb = (t * 16 + c) * 16 + 4 * (q ^ hc);
                *(uint2*)&s_wfh[p][eb] = make_uint2(u01, u23);
            }
        }
    }
    __syncthreads();

    // ---- ph3: offsets via f16 MFMA (A = wf1 fp16, B = compensated ow);   ----
    // ---- 16 real A rows (points), contraction split over 8 waves (4 ks) ----
    {
        const int pr = lane & 15;                    // A row = point
        f32x4 acc0 = {0,0,0,0}, acc1 = {0,0,0,0}, acc2 = {0,0,0,0};
#pragma unroll
        for (int s = 0; s < 4; s++) {
            const int ks = wid * 4 + s;
            const f16x8 ahh = *(const f16x8*)&s_wfh[pr][ks * 32 + q * 8];
#pragma unroll
            for (int nt = 0; nt < 3; nt++) {
                const int f = ((ks * 3 + nt) * 64 + lane) * 8;
                const f16x8 bh = *(const f16x8*)&owh[f];
                const f16x8 bl = *(const f16x8*)&owl[f];
                f32x4* acc = (nt == 0) ? &acc0 : (nt == 1) ? &acc1 : &acc2;
                *acc = __builtin_amdgcn_mfma_f32_16x16x32_f16(ahh, bh, *acc, 0, 0, 0);
                *acc = __builtin_amdgcn_mfma_f32_16x16x32_f16(ahh, bl, *acc, 0, 0, 0);
            }
        }
        __syncthreads();   // part3 ALIASES wfh: all waves' wf1 reads must finish
#pragma unroll
        for (int r = 0; r < 4; r++) {
            s_part3[wid][4 * q + r][0 * 16 + c] = acc0[r];
            s_part3[wid][4 * q + r][1 * 16 + c] = acc1[r];
            s_part3[wid][4 * q + r][2 * 16 + c] = acc2[r];
        }
    }
    __syncthreads();

    // ---- reduce 8 ks-partials + bias -> offsets (fp32) ----
    for (int idx = tid; idx < P * E1; idx += 512) {
        const int p = idx / E1, e = idx % E1;
        float v = obias[e];
#pragma unroll
        for (int w8 = 0; w8 < 8; w8++)
            v += s_part3[w8][p][e];
        s_off[p][e] = v;
    }
    __syncthreads();

    // ---- ph5: aw2 (deformed) -> padded plane slots of wfh[pg] + wave mask ----
    {
        unsigned pmask = 0;
        float av[16];
        av[15] = 0.f;
#pragma unroll
        for (int k = 0; k < KP; k++) {
            const float kx = kpts[k * 3 + 0] + s_off[pg][3 * k + 0];
            const float ky = kpts[k * 3 + 1] + s_off[pg][3 * k + 1];
            const float kz = kpts[k * 3 + 2] + s_off[pg][3 * k + 2];
            const float dx = nbx - kx, dy = nby - ky, dz = nbz - kz;
            av[k] = fmaxf(1.0f - fsqrt_fast(dx * dx + dy * dy + dz * dz), 0.f);
            pmask |= (__ballot(av[k] > 0.f) ? 1u : 0u) << k;   // union of wave's 2 pts
        }
        unsigned short* awp = &s_wfh[pg][0];
#pragma unroll
        for (int k2 = 0; k2 < 16; k2 += 2) {
            const unsigned hu = pkrne(av[k2], av[k2 + 1]);
            awp[k2 * AWR + mg]       = (unsigned short)hu;
            awp[(k2 + 1) * AWR + mg] = (unsigned short)(hu >> 16);
        }
        if (lane == 0) *(unsigned*)&s_wfh[wid][1024] = pmask;  // pad-hole s_act
    }
    // no barrier: ph6 wave reads only its own aw writes; holes read after barrier

    // ---- ph6: wf2 via single f16 MFMA, operands swapped (D[d][k]) ----
    {
#pragma unroll
        for (int pi = 0; pi < 2; pi++) {
            const int p = 2 * wid + pi;
            // consume aw2[p] fully, then overwrite plane with wf2 enum
            const f16x8 awh_f = *(const f16x8*)&s_wfh[p][(lane & 15) * AWR + q * 8];
#pragma unroll
            for (int t = 0; t < 4; t++) {
                f32x4 dacc = {0.f, 0.f, 0.f, 0.f};
                dacc = __builtin_amdgcn_mfma_f32_16x16x32_f16(fbh[pi][t], awh_f, dacc, 0, 0, 0);
                // wf2[k=c][d = t*16+4q+r] single fp16 (RNE); dsw keeps 4-runs
                const unsigned u01 = pkrne(dacc[0], dacc[1]);
                const unsigned u23 = pkrne(dacc[2], dacc[3]);
                const int dsw = (t * 16 + 4 * q) ^ ((c & 7) << 3);
                *(uint2*)&s_wfh[p][c * 64 + dsw] = make_uint2(u01, u23);
            }
        }
    }
    __syncthreads();

    unsigned u2 = 0;
#pragma unroll
    for (int w = 0; w < 8; w++) u2 |= *(const unsigned*)&s_wfh[w][1024];

    // ---- ph7: output via single f16 MFMA over active k ----
    // wave = (etile, kh): 4 e-tiles x 2 kk-halves; kh pair summed via LDS.
    {
        const int etile = wid & 3, kh = wid >> 2;
        const int pr = lane & 15;                   // A row = point (16 real rows)
        f32x4 acc = {0.f, 0.f, 0.f, 0.f};
#pragma unroll
        for (int k = 0; k < KP; k++) {
            if (!((u2 >> k) & 1)) continue;
            const int ks = k * 2 + kh;              // this wave's kk half
            const f16x8 ah = *(const f16x8*)&s_wfh[pr][ks * 32 + q * 8];
            const f16x8 bh = *(const f16x8*)&wh[((ks * 4 + etile) * 64 + lane) * 8];
            acc = __builtin_amdgcn_mfma_f32_16x16x32_f16(ah, bh, acc, 0, 0, 0);
        }
        // misc block (nbr/q/off) dead by ph7 -> s_red[4][16][16] kk-half staging
        if (kh == 1) {
#pragma unroll
            for (int r = 0; r < 4; r++)
                s_red[etile][4 * q + r][c] = acc[r];
        }
        __syncthreads();
        if (kh == 0) {
#pragma unroll
            for (int r = 0; r < 4; r++)
                out[(base + 4 * q + r) * D + etile * 16 + c] =
                    acc[r] + s_red[etile][4 * q + r][c];
        }
    }
}

extern "C" void kernel_launch(void* const* d_in, const int* in_sizes, int n_in,
                              void* d_out, int out_size, void* d_ws, size_t ws_size,
                              hipStream_t stream) {
    const float* q   = (const float*)d_in[0];
    const float* s   = (const float*)d_in[1];
    const int*   nb  = (const int*)  d_in[2];
    const float* x   = (const float*)d_in[3];
    const float* kp  = (const float*)d_in[4];
    const float* ow  = (const float*)d_in[5];
    const float* ob  = (const float*)d_in[6];
    const float* w   = (const float*)d_in[7];
    float* out = (float*)d_out;

    // xw fp16-only: 6,400,000 B used of its region (offsets kept stable)
    unsigned*       xw  = (unsigned*)d_ws;
    unsigned short* owh = (unsigned short*)((char*)d_ws + 12800000);  //     98,304 B
    unsigned short* owl = (unsigned short*)((char*)d_ws + 12898304);  //     98,304 B
    unsigned short* wh  = (unsigned short*)((char*)d_ws + 12996608);  //    122,880 B

    prep_all<<<3557, 256, 0, stream>>>(x, ow, w, xw, owh, owl, wh);
    kpconv_deform<<<N_PTS / P, 512, 0, stream>>>(q, s, nb, kp, ob,
                                                 xw, owh, owl, wh, out);
}